// Round 1
// baseline (3009.572 us; speedup 1.0000x reference)
//
#include <hip/hip_runtime.h>

#define NB 64
#define NO 100
#define NI 2048
#define ND 16
#define NK 8

// ws layout (float offsets)
#define WS_H    0            // h: 64*256*24*24 = 9437184
#define WS_U    9437184      // p/u: 64*2048*8 = 1048576 (squashed in place)
#define WS_BB   10485760     // b logits: 64*100*2048 = 13107200
#define WS_CB   23592960     // c: 13107200
#define WS_SP   36700160     // s partials: 100*16*64*16 = 1638400
#define WS_V    38338560     // v: 64*100*16 = 102400
// total 38440960 floats = 153.8 MB

// ---------------- conv1: [64,3,32,32] -> relu -> [64,256,24,24] ----------------
__global__ __launch_bounds__(256) void conv1_kernel(const float* __restrict__ x,
        const float* __restrict__ w, const float* __restrict__ bias,
        float* __restrict__ h) {
    const int b = blockIdx.x;
    const int ocg = blockIdx.y;          // 16 oc per block
    __shared__ float xl[3 * 32 * 32];
    __shared__ float wl[16 * 243];
    const int tid = threadIdx.x;
    for (int idx = tid; idx < 3072; idx += 256) xl[idx] = x[b * 3072 + idx];
    for (int idx = tid; idx < 16 * 243; idx += 256)
        wl[idx] = w[ocg * 16 * 243 + idx];
    __syncthreads();
    const int lane = tid & 63;
    const int wg = tid >> 6;             // 0..3 -> 4 oc each
    float acc[4][9];
    #pragma unroll
    for (int jj = 0; jj < 4; ++jj) {
        float bv = bias[ocg * 16 + wg * 4 + jj];
        #pragma unroll
        for (int j = 0; j < 9; ++j) acc[jj][j] = bv;
    }
    int xbase[9];
    #pragma unroll
    for (int j = 0; j < 9; ++j) {
        int p = lane + 64 * j;           // 576 positions exactly
        xbase[j] = (p / 24) * 32 + (p % 24);
    }
    for (int ic = 0; ic < 3; ++ic)
        for (int ky = 0; ky < 9; ++ky) {
            #pragma unroll
            for (int kx = 0; kx < 9; ++kx) {
                float wv[4];
                #pragma unroll
                for (int jj = 0; jj < 4; ++jj)
                    wv[jj] = wl[(wg * 4 + jj) * 243 + ic * 81 + ky * 9 + kx];
                #pragma unroll
                for (int j = 0; j < 9; ++j) {
                    float xv = xl[ic * 1024 + xbase[j] + ky * 32 + kx];
                    #pragma unroll
                    for (int jj = 0; jj < 4; ++jj)
                        acc[jj][j] = fmaf(xv, wv[jj], acc[jj][j]);
                }
            }
        }
    #pragma unroll
    for (int jj = 0; jj < 4; ++jj) {
        int oc = ocg * 16 + wg * 4 + jj;
        #pragma unroll
        for (int j = 0; j < 9; ++j) {
            int p = lane + 64 * j;
            h[(b * 256 + oc) * 576 + p] = fmaxf(acc[jj][j], 0.f);
        }
    }
}

// ---------------- conv2: [64,256,24,24] -> [64,256,8,8] (+bias) ----------------
__global__ __launch_bounds__(128) void conv2_kernel(const float* __restrict__ h,
        const float* __restrict__ w, const float* __restrict__ bias,
        float* __restrict__ p_out) {
    const int b = blockIdx.x;
    const int ocb = blockIdx.y;          // 8 blocks of 32 oc
    __shared__ float xl[2 * 576];        // [2 ic][24][24]
    __shared__ __align__(16) float wl[162 * 36];  // [kk][oc], pad 36 (16B-aligned fl4)
    const int tid = threadIdx.x;
    const int poslane = tid & 15;
    const int ocg = tid >> 4;            // 0..7 -> 4 oc each
    float acc[4][4];
    #pragma unroll
    for (int a = 0; a < 4; ++a)
        #pragma unroll
        for (int c = 0; c < 4; ++c) acc[a][c] = 0.f;
    int pb[4];
    #pragma unroll
    for (int j = 0; j < 4; ++j) {
        int p = poslane + 16 * j;
        pb[j] = 2 * ((p >> 3) * 24 + (p & 7));
    }
    for (int ic0 = 0; ic0 < 256; ic0 += 2) {
        __syncthreads();
        for (int idx = tid; idx < 1152; idx += 128)
            xl[idx] = h[(b * 256 + ic0) * 576 + idx];
        for (int idx = tid; idx < 5184; idx += 128) {
            int oc = idx / 162, kk = idx % 162;
            wl[kk * 36 + oc] = w[(ocb * 32 + oc) * 20736 + ic0 * 81 + kk];
        }
        __syncthreads();
        for (int e = 0; e < 2; ++e) {
            for (int ky = 0; ky < 9; ++ky) {
                #pragma unroll
                for (int kx = 0; kx < 9; ++kx) {
                    int kk = e * 81 + ky * 9 + kx;
                    const float4 wv = *(const float4*)&wl[kk * 36 + ocg * 4];
                    #pragma unroll
                    for (int j = 0; j < 4; ++j) {
                        float xv = xl[e * 576 + ky * 24 + kx + pb[j]];
                        acc[0][j] = fmaf(wv.x, xv, acc[0][j]);
                        acc[1][j] = fmaf(wv.y, xv, acc[1][j]);
                        acc[2][j] = fmaf(wv.z, xv, acc[2][j]);
                        acc[3][j] = fmaf(wv.w, xv, acc[3][j]);
                    }
                }
            }
        }
    }
    #pragma unroll
    for (int jj = 0; jj < 4; ++jj) {
        int oc = ocb * 32 + ocg * 4 + jj;
        float bv = bias[oc];
        #pragma unroll
        for (int j = 0; j < 4; ++j) {
            int p = poslane + 16 * j;
            p_out[(b * 256 + oc) * 64 + p] = acc[jj][j] + bv;
        }
    }
}

// ---------------- squash primary capsules in place: rows of 8 ----------------
__global__ __launch_bounds__(256) void squash_u_kernel(float* __restrict__ u) {
    const int row = blockIdx.x * 256 + threadIdx.x;    // 131072 rows
    float4 a = *(float4*)&u[row * 8];
    float4 c = *(float4*)&u[row * 8 + 4];
    float s2 = a.x * a.x + a.y * a.y + a.z * a.z + a.w * a.w
             + c.x * c.x + c.y * c.y + c.z * c.z + c.w * c.w;
    float scale = (s2 / (1.f + s2)) / sqrtf(s2 + 1e-8f);
    a.x *= scale; a.y *= scale; a.z *= scale; a.w *= scale;
    c.x *= scale; c.y *= scale; c.z *= scale; c.w *= scale;
    *(float4*)&u[row * 8] = a;
    *(float4*)&u[row * 8 + 4] = c;
}

// -------- weighted sum: s_part[o][st][b][d] = sum_i c[b,o,i]*u_hat[b,o,i,d] --------
template <int UNIFORM>
__global__ __launch_bounds__(256) void r_weighted_kernel(
        const float* __restrict__ W, const float* __restrict__ u,
        const float* __restrict__ cbuf, float* __restrict__ sp) {
    const int o = blockIdx.x;
    const int st = blockIdx.y;                 // 16 supertiles of 128 i
    __shared__ __align__(16) float Wl[16 * 128];   // [ii][d][k]
    __shared__ __align__(16) float ul[64 * 128];   // [b][ii][k]
    __shared__ float cl[64 * 16];                  // [b][ii]
    const int tid = threadIdx.x;
    const int d = tid & 15;
    const int bg = tid >> 4;
    float acc[4] = {0.f, 0.f, 0.f, 0.f};
    for (int sub = 0; sub < 8; ++sub) {
        const int i0 = st * 128 + sub * 16;
        __syncthreads();
        for (int idx = tid; idx < 2048; idx += 256)
            Wl[idx] = W[o * 262144 + i0 * 128 + idx];
        for (int idx = tid; idx < 8192; idx += 256) {
            int bb = idx >> 7, r = idx & 127;
            ul[idx] = u[bb * 16384 + i0 * 8 + r];
        }
        if (!UNIFORM) {
            for (int idx = tid; idx < 1024; idx += 256) {
                int bb = idx >> 4, ii = idx & 15;
                cl[idx] = cbuf[bb * (NO * NI) + o * NI + i0 + ii];
            }
        }
        __syncthreads();
        for (int ii = 0; ii < 16; ++ii) {
            const float4 wa = *(const float4*)&Wl[ii * 128 + d * 8];
            const float4 wb = *(const float4*)&Wl[ii * 128 + d * 8 + 4];
            #pragma unroll
            for (int j = 0; j < 4; ++j) {
                const int bb = bg + 16 * j;
                const float4 ua = *(const float4*)&ul[bb * 128 + ii * 8];
                const float4 ub = *(const float4*)&ul[bb * 128 + ii * 8 + 4];
                float uh = wa.x * ua.x + wa.y * ua.y + wa.z * ua.z + wa.w * ua.w
                         + wb.x * ub.x + wb.y * ub.y + wb.z * ub.z + wb.w * ub.w;
                float cv = UNIFORM ? 0.01f : cl[bb * 16 + ii];
                acc[j] = fmaf(cv, uh, acc[j]);
            }
        }
    }
    #pragma unroll
    for (int j = 0; j < 4; ++j) {
        const int bb = bg + 16 * j;
        sp[((o * 16 + st) * 64 + bb) * 16 + d] = acc[j];
    }
}

// -------- reduce partials over st, squash over d, write v (or final out) --------
__global__ __launch_bounds__(256) void squash_v_kernel(const float* __restrict__ sp,
        float* __restrict__ dest) {
    const int t = blockIdx.x * 256 + threadIdx.x;  // 102400 slots
    const int d = t & 15;
    const int cap = t >> 4;                        // o*64 + b
    const int o = cap >> 6;
    const int bb = cap & 63;
    float s = 0.f;
    #pragma unroll
    for (int st = 0; st < 16; ++st)
        s += sp[((o * 16 + st) * 64 + bb) * 16 + d];
    float s2 = s * s;
    #pragma unroll
    for (int off = 1; off < 16; off <<= 1)
        s2 += __shfl_xor(s2, off, 16);
    float scale = (s2 / (1.f + s2)) / sqrtf(s2 + 1e-8f);
    dest[(bb * NO + o) * ND + d] = s * scale;
}

// -------- logits: b[b,o,i] (+)= sum_d u_hat[b,o,i,d] * v[b,o,d] --------
template <int ADD>
__global__ __launch_bounds__(256) void r_logits_kernel(
        const float* __restrict__ W, const float* __restrict__ u,
        const float* __restrict__ v, float* __restrict__ bbuf) {
    const int o = blockIdx.x;
    const int st = blockIdx.y;
    __shared__ __align__(16) float Wl[16 * 128];
    __shared__ __align__(16) float ul[64 * 128];
    __shared__ float vl[64 * 16];
    const int tid = threadIdx.x;
    const int ii = tid & 15;
    const int bg = tid >> 4;
    for (int idx = tid; idx < 1024; idx += 256) {
        int bb = idx >> 4, dd = idx & 15;
        vl[idx] = v[(bb * NO + o) * ND + dd];
    }
    for (int sub = 0; sub < 8; ++sub) {
        const int i0 = st * 128 + sub * 16;
        __syncthreads();
        for (int idx = tid; idx < 2048; idx += 256)
            Wl[idx] = W[o * 262144 + i0 * 128 + idx];
        for (int idx = tid; idx < 8192; idx += 256) {
            int bb = idx >> 7, r = idx & 127;
            ul[idx] = u[bb * 16384 + i0 * 8 + r];
        }
        __syncthreads();
        float4 ua[4], ub[4];
        #pragma unroll
        for (int j = 0; j < 4; ++j) {
            const int bb = bg + 16 * j;
            ua[j] = *(const float4*)&ul[bb * 128 + ii * 8];
            ub[j] = *(const float4*)&ul[bb * 128 + ii * 8 + 4];
        }
        float tmp[4] = {0.f, 0.f, 0.f, 0.f};
        for (int dd = 0; dd < 16; ++dd) {
            const float4 wa = *(const float4*)&Wl[ii * 128 + dd * 8];
            const float4 wb = *(const float4*)&Wl[ii * 128 + dd * 8 + 4];
            #pragma unroll
            for (int j = 0; j < 4; ++j) {
                float uh = wa.x * ua[j].x + wa.y * ua[j].y + wa.z * ua[j].z + wa.w * ua[j].w
                         + wb.x * ub[j].x + wb.y * ub[j].y + wb.z * ub[j].z + wb.w * ub[j].w;
                tmp[j] = fmaf(uh, vl[(bg + 16 * j) * 16 + dd], tmp[j]);
            }
        }
        #pragma unroll
        for (int j = 0; j < 4; ++j) {
            const int bb = bg + 16 * j;
            const int addr = bb * (NO * NI) + o * NI + i0 + ii;
            bbuf[addr] = (ADD ? bbuf[addr] : 0.f) + tmp[j];
        }
    }
}

// -------- softmax over o (axis=1) of b -> c --------
__global__ __launch_bounds__(256) void softmax_kernel(const float* __restrict__ bbuf,
        float* __restrict__ cbuf) {
    const int bb = blockIdx.x >> 3;
    const int i = (blockIdx.x & 7) * 256 + threadIdx.x;
    const float* col = bbuf + bb * (NO * NI) + i;
    float m = -1e30f;
    for (int o = 0; o < NO; ++o) m = fmaxf(m, col[o * NI]);
    float s = 0.f;
    for (int o = 0; o < NO; ++o) s += __expf(col[o * NI] - m);
    const float inv = 1.f / s;
    float* outp = cbuf + bb * (NO * NI) + i;
    for (int o = 0; o < NO; ++o) outp[o * NI] = __expf(col[o * NI] - m) * inv;
}

extern "C" void kernel_launch(void* const* d_in, const int* in_sizes, int n_in,
                              void* d_out, int out_size, void* d_ws, size_t ws_size,
                              hipStream_t stream) {
    (void)in_sizes; (void)n_in; (void)out_size; (void)ws_size;
    const float* x      = (const float*)d_in[0];
    const float* conv_w = (const float*)d_in[1];
    const float* conv_b = (const float*)d_in[2];
    const float* pcap_w = (const float*)d_in[3];
    const float* pcap_b = (const float*)d_in[4];
    const float* W      = (const float*)d_in[5];
    float* out = (float*)d_out;
    float* ws  = (float*)d_ws;
    float* h   = ws + WS_H;
    float* u   = ws + WS_U;
    float* bbf = ws + WS_BB;
    float* cbf = ws + WS_CB;
    float* sp  = ws + WS_SP;
    float* v   = ws + WS_V;

    conv1_kernel<<<dim3(64, 16), 256, 0, stream>>>(x, conv_w, conv_b, h);
    conv2_kernel<<<dim3(64, 8), 128, 0, stream>>>(h, pcap_w, pcap_b, u);
    squash_u_kernel<<<512, 256, 0, stream>>>(u);
    // routing iter 0 (c uniform = 1/100)
    r_weighted_kernel<1><<<dim3(100, 16), 256, 0, stream>>>(W, u, nullptr, sp);
    squash_v_kernel<<<400, 256, 0, stream>>>(sp, v);
    r_logits_kernel<0><<<dim3(100, 16), 256, 0, stream>>>(W, u, v, bbf);
    // routing iter 1
    softmax_kernel<<<512, 256, 0, stream>>>(bbf, cbf);
    r_weighted_kernel<0><<<dim3(100, 16), 256, 0, stream>>>(W, u, cbf, sp);
    squash_v_kernel<<<400, 256, 0, stream>>>(sp, v);
    r_logits_kernel<1><<<dim3(100, 16), 256, 0, stream>>>(W, u, v, bbf);
    // routing iter 2
    softmax_kernel<<<512, 256, 0, stream>>>(bbf, cbf);
    r_weighted_kernel<0><<<dim3(100, 16), 256, 0, stream>>>(W, u, cbf, sp);
    squash_v_kernel<<<400, 256, 0, stream>>>(sp, out);
}

// Round 4
// 1889.131 us; speedup vs baseline: 1.5931x; 1.5931x over previous
//
#include <hip/hip_runtime.h>

#define NB 64
#define NO 100
#define NI 2048
#define ND 16
#define NK 8

// ws layout (float offsets)
#define WS_H    0            // h: 64*256*24*24 = 9437184
#define WS_U    9437184      // u: 64*2048*8 = 1048576
#define WS_BB   10485760     // b logits: 64*100*2048 = 13107200  (pp overlaps here pre-routing)
#define WS_CB   23592960     // c: 13107200                        (wT overlaps here pre-routing)
#define WS_SP   36700160     // s partials: 100*16*64*16 = 1638400
#define WS_V    38338560     // v: 64*100*16 = 102400
// total 38440960 floats = 153.8 MB
#define WS_PP   WS_BB        // conv2 partials: 8*64*256*64 = 8388608
#define WS_WT   WS_CB        // wT: 256*81*256 = 5308416

// ---------------- conv1: [64,3,32,32] -> relu -> [64,256,24,24] ----------------
__global__ __launch_bounds__(256) void conv1_kernel(const float* __restrict__ x,
        const float* __restrict__ w, const float* __restrict__ bias,
        float* __restrict__ h) {
    const int b = blockIdx.x;
    const int ocg = blockIdx.y;          // 16 oc per block
    __shared__ float xl[3 * 32 * 32];
    __shared__ float wl[16 * 243];
    const int tid = threadIdx.x;
    for (int idx = tid; idx < 3072; idx += 256) xl[idx] = x[b * 3072 + idx];
    for (int idx = tid; idx < 16 * 243; idx += 256)
        wl[idx] = w[ocg * 16 * 243 + idx];
    __syncthreads();
    const int lane = tid & 63;
    const int wg = tid >> 6;             // 0..3 -> 4 oc each
    float acc[4][9];
    #pragma unroll
    for (int jj = 0; jj < 4; ++jj) {
        float bv = bias[ocg * 16 + wg * 4 + jj];
        #pragma unroll
        for (int j = 0; j < 9; ++j) acc[jj][j] = bv;
    }
    int xbase[9];
    #pragma unroll
    for (int j = 0; j < 9; ++j) {
        int p = lane + 64 * j;           // 576 positions exactly
        xbase[j] = (p / 24) * 32 + (p % 24);
    }
    for (int ic = 0; ic < 3; ++ic)
        for (int ky = 0; ky < 9; ++ky) {
            #pragma unroll
            for (int kx = 0; kx < 9; ++kx) {
                float wv[4];
                #pragma unroll
                for (int jj = 0; jj < 4; ++jj)
                    wv[jj] = wl[(wg * 4 + jj) * 243 + ic * 81 + ky * 9 + kx];
                #pragma unroll
                for (int j = 0; j < 9; ++j) {
                    float xv = xl[ic * 1024 + xbase[j] + ky * 32 + kx];
                    #pragma unroll
                    for (int jj = 0; jj < 4; ++jj)
                        acc[jj][j] = fmaf(xv, wv[jj], acc[jj][j]);
                }
            }
        }
    #pragma unroll
    for (int jj = 0; jj < 4; ++jj) {
        int oc = ocg * 16 + wg * 4 + jj;
        #pragma unroll
        for (int j = 0; j < 9; ++j) {
            int p = lane + 64 * j;
            h[(b * 256 + oc) * 576 + p] = fmaxf(acc[jj][j], 0.f);
        }
    }
}

// ---------------- transpose pcap_w -> wT[ic][kk][oc] ----------------
__global__ __launch_bounds__(256) void transpose_w_kernel(const float* __restrict__ w,
        float* __restrict__ wT) {
    const int ic = blockIdx.x;           // 0..255
    const int ocq = blockIdx.y;          // 0..3 (64 oc each)
    __shared__ float tl[64][85];         // pad 85: gcd(21,32)=1, conflict-free
    const int tid = threadIdx.x;
    for (int f = tid; f < 5184; f += 256) {
        int oc = f / 81, kk = f % 81;
        tl[oc][kk] = w[(size_t)(ocq * 64 + oc) * 20736 + ic * 81 + kk];
    }
    __syncthreads();
    for (int f = tid; f < 5184; f += 256) {
        int kk = f >> 6, oc = f & 63;
        wT[((size_t)ic * 81 + kk) * 256 + ocq * 64 + oc] = tl[oc][kk];
    }
}

// ---------------- conv2 partial: K-split implicit GEMM ----------------
// block: 64 oc x 128 pos (2 batches) x 32-ic slice. thread: 8 oc x 4 pos.
__global__ __launch_bounds__(256, 4) void conv2_partial_kernel(
        const float* __restrict__ h, const float* __restrict__ wT,
        float* __restrict__ pp) {
    const int bpair = blockIdx.x;        // 0..31
    const int ocb = blockIdx.y;          // 0..3  (64 oc)
    const int ks = blockIdx.z;           // 0..7  (32 ic)
    __shared__ __align__(16) float wl[81 * 64];   // [kk][oc] linear
    __shared__ __align__(16) float xl[2 * 576];   // [bhalf][24*24]
    const int tid = threadIdx.x;
    const int ocg = tid & 7;             // 8 oc groups of 8
    const int posg = tid >> 3;           // 0..31
    const int bh = posg >> 4;            // batch half
    const int sub = posg & 15;
    const int oy = sub >> 1;             // output row 0..7
    const int ox0 = (sub & 1) * 4;       // output col base 0 or 4
    float acc[8][4];
    #pragma unroll
    for (int j = 0; j < 8; ++j)
        #pragma unroll
        for (int p = 0; p < 4; ++p) acc[j][p] = 0.f;
    const int ic0 = ks * 32;
    #pragma unroll 1
    for (int ic = ic0; ic < ic0 + 32; ++ic) {
        __syncthreads();
        // stage weights: 81 rows x 64 oc = 1296 float4, coalesced, LDS-linear
        const float4* wsrc = (const float4*)(wT + ((size_t)ic * 81) * 256 + ocb * 64);
        for (int it = tid; it < 1296; it += 256)
            ((float4*)wl)[it] = wsrc[(it >> 4) * 64 + (it & 15)];
        // stage x: 2 batches x 576 = 288 float4
        for (int it = tid; it < 288; it += 256) {
            int b2 = (it >= 144);
            int idx = it - b2 * 144;
            ((float4*)xl)[it] =
                ((const float4*)(h + ((size_t)(bpair * 2 + b2) * 256 + ic) * 576))[idx];
        }
        __syncthreads();
        const float* xb = xl + bh * 576;
        #pragma unroll
        for (int ky = 0; ky < 9; ++ky) {
            const float* xrow = xb + (2 * oy + ky) * 24 + 2 * ox0;
            #pragma unroll
            for (int kx = 0; kx < 9; ++kx) {
                const int kk = ky * 9 + kx;
                const float4 wa = *(const float4*)&wl[kk * 64 + ocg * 8];
                const float4 wb = *(const float4*)&wl[kk * 64 + ocg * 8 + 4];
                float xv[4];
                #pragma unroll
                for (int p = 0; p < 4; ++p) xv[p] = xrow[2 * p + kx];
                #pragma unroll
                for (int p = 0; p < 4; ++p) {
                    acc[0][p] = fmaf(wa.x, xv[p], acc[0][p]);
                    acc[1][p] = fmaf(wa.y, xv[p], acc[1][p]);
                    acc[2][p] = fmaf(wa.z, xv[p], acc[2][p]);
                    acc[3][p] = fmaf(wa.w, xv[p], acc[3][p]);
                    acc[4][p] = fmaf(wb.x, xv[p], acc[4][p]);
                    acc[5][p] = fmaf(wb.y, xv[p], acc[5][p]);
                    acc[6][p] = fmaf(wb.z, xv[p], acc[6][p]);
                    acc[7][p] = fmaf(wb.w, xv[p], acc[7][p]);
                }
            }
        }
    }
    const int b = bpair * 2 + bh;
    #pragma unroll
    for (int j = 0; j < 8; ++j) {
        const int oc = ocb * 64 + ocg * 8 + j;
        #pragma unroll
        for (int p = 0; p < 4; ++p) {
            const int pos = oy * 8 + ox0 + p;
            pp[(((size_t)ks * 64 + b) * 256 + oc) * 64 + pos] = acc[j][p];
        }
    }
}

// -------- reduce partials over ks, +bias, squash capsule rows of 8 -> u --------
__global__ __launch_bounds__(256) void reduce_bias_squash_kernel(
        const float* __restrict__ pp, const float* __restrict__ bias,
        float* __restrict__ u) {
    const int cap = blockIdx.x * 256 + threadIdx.x;   // 131072 capsules
    const int b = cap >> 11;
    const int rem = cap & 2047;
    const int oc = rem >> 3;
    const int oy = rem & 7;
    float4 sa = {0.f, 0.f, 0.f, 0.f}, sb = {0.f, 0.f, 0.f, 0.f};
    #pragma unroll
    for (int ks = 0; ks < 8; ++ks) {
        const float4* p4 = (const float4*)&pp[(((size_t)ks * 64 + b) * 256 + oc) * 64 + oy * 8];
        float4 a = p4[0], c = p4[1];
        sa.x += a.x; sa.y += a.y; sa.z += a.z; sa.w += a.w;
        sb.x += c.x; sb.y += c.y; sb.z += c.z; sb.w += c.w;
    }
    const float bv = bias[oc];
    sa.x += bv; sa.y += bv; sa.z += bv; sa.w += bv;
    sb.x += bv; sb.y += bv; sb.z += bv; sb.w += bv;
    float s2 = sa.x * sa.x + sa.y * sa.y + sa.z * sa.z + sa.w * sa.w
             + sb.x * sb.x + sb.y * sb.y + sb.z * sb.z + sb.w * sb.w;
    float scale = (s2 / (1.f + s2)) / sqrtf(s2 + 1e-8f);
    sa.x *= scale; sa.y *= scale; sa.z *= scale; sa.w *= scale;
    sb.x *= scale; sb.y *= scale; sb.z *= scale; sb.w *= scale;
    float4* up = (float4*)&u[(size_t)cap * 8];
    up[0] = sa;
    up[1] = sb;
}

// -------- weighted sum: s_part[o][st][b][d] = sum_i c[b,o,i]*u_hat[b,o,i,d] --------
template <int UNIFORM>
__global__ __launch_bounds__(256) void r_weighted_kernel(
        const float* __restrict__ W, const float* __restrict__ u,
        const float* __restrict__ cbuf, float* __restrict__ sp) {
    const int o = blockIdx.x;
    const int st = blockIdx.y;                 // 16 supertiles of 128 i
    __shared__ __align__(16) float Wl[16 * 128];   // [ii][d][k]
    __shared__ __align__(16) float ul[64 * 128];   // [b][ii][k]
    __shared__ float cl[64 * 16];                  // [b][ii]
    const int tid = threadIdx.x;
    const int d = tid & 15;
    const int bg = tid >> 4;
    float acc[4] = {0.f, 0.f, 0.f, 0.f};
    for (int sub = 0; sub < 8; ++sub) {
        const int i0 = st * 128 + sub * 16;
        __syncthreads();
        for (int idx = tid; idx < 2048; idx += 256)
            Wl[idx] = W[o * 262144 + i0 * 128 + idx];
        for (int idx = tid; idx < 8192; idx += 256) {
            int bb = idx >> 7, r = idx & 127;
            ul[idx] = u[bb * 16384 + i0 * 8 + r];
        }
        if (!UNIFORM) {
            for (int idx = tid; idx < 1024; idx += 256) {
                int bb = idx >> 4, ii = idx & 15;
                cl[idx] = cbuf[bb * (NO * NI) + o * NI + i0 + ii];
            }
        }
        __syncthreads();
        for (int ii = 0; ii < 16; ++ii) {
            const float4 wa = *(const float4*)&Wl[ii * 128 + d * 8];
            const float4 wb = *(const float4*)&Wl[ii * 128 + d * 8 + 4];
            #pragma unroll
            for (int j = 0; j < 4; ++j) {
                const int bb = bg + 16 * j;
                const float4 ua = *(const float4*)&ul[bb * 128 + ii * 8];
                const float4 ub = *(const float4*)&ul[bb * 128 + ii * 8 + 4];
                float uh = wa.x * ua.x + wa.y * ua.y + wa.z * ua.z + wa.w * ua.w
                         + wb.x * ub.x + wb.y * ub.y + wb.z * ub.z + wb.w * ub.w;
                float cv = UNIFORM ? 0.01f : cl[bb * 16 + ii];
                acc[j] = fmaf(cv, uh, acc[j]);
            }
        }
    }
    #pragma unroll
    for (int j = 0; j < 4; ++j) {
        const int bb = bg + 16 * j;
        sp[((o * 16 + st) * 64 + bb) * 16 + d] = acc[j];
    }
}

// -------- reduce partials over st, squash over d, write v (or final out) --------
__global__ __launch_bounds__(256) void squash_v_kernel(const float* __restrict__ sp,
        float* __restrict__ dest) {
    const int t = blockIdx.x * 256 + threadIdx.x;  // 102400 slots
    const int d = t & 15;
    const int cap = t >> 4;                        // o*64 + b
    const int o = cap >> 6;
    const int bb = cap & 63;
    float s = 0.f;
    #pragma unroll
    for (int st = 0; st < 16; ++st)
        s += sp[((o * 16 + st) * 64 + bb) * 16 + d];
    float s2 = s * s;
    #pragma unroll
    for (int off = 1; off < 16; off <<= 1)
        s2 += __shfl_xor(s2, off, 16);
    float scale = (s2 / (1.f + s2)) / sqrtf(s2 + 1e-8f);
    dest[(bb * NO + o) * ND + d] = s * scale;
}

// -------- logits: b[b,o,i] (+)= sum_d u_hat[b,o,i,d] * v[b,o,d] --------
template <int ADD>
__global__ __launch_bounds__(256) void r_logits_kernel(
        const float* __restrict__ W, const float* __restrict__ u,
        const float* __restrict__ v, float* __restrict__ bbuf) {
    const int o = blockIdx.x;
    const int st = blockIdx.y;
    __shared__ __align__(16) float Wl[16 * 128];
    __shared__ __align__(16) float ul[64 * 128];
    __shared__ float vl[64 * 16];
    const int tid = threadIdx.x;
    const int ii = tid & 15;
    const int bg = tid >> 4;
    for (int idx = tid; idx < 1024; idx += 256) {
        int bb = idx >> 4, dd = idx & 15;
        vl[idx] = v[(bb * NO + o) * ND + dd];
    }
    for (int sub = 0; sub < 8; ++sub) {
        const int i0 = st * 128 + sub * 16;
        __syncthreads();
        for (int idx = tid; idx < 2048; idx += 256)
            Wl[idx] = W[o * 262144 + i0 * 128 + idx];
        for (int idx = tid; idx < 8192; idx += 256) {
            int bb = idx >> 7, r = idx & 127;
            ul[idx] = u[bb * 16384 + i0 * 8 + r];
        }
        __syncthreads();
        float4 ua[4], ub[4];
        #pragma unroll
        for (int j = 0; j < 4; ++j) {
            const int bb = bg + 16 * j;
            ua[j] = *(const float4*)&ul[bb * 128 + ii * 8];
            ub[j] = *(const float4*)&ul[bb * 128 + ii * 8 + 4];
        }
        float tmp[4] = {0.f, 0.f, 0.f, 0.f};
        for (int dd = 0; dd < 16; ++dd) {
            const float4 wa = *(const float4*)&Wl[ii * 128 + dd * 8];
            const float4 wb = *(const float4*)&Wl[ii * 128 + dd * 8 + 4];
            #pragma unroll
            for (int j = 0; j < 4; ++j) {
                float uh = wa.x * ua[j].x + wa.y * ua[j].y + wa.z * ua[j].z + wa.w * ua[j].w
                         + wb.x * ub[j].x + wb.y * ub[j].y + wb.z * ub[j].z + wb.w * ub[j].w;
                tmp[j] = fmaf(uh, vl[(bg + 16 * j) * 16 + dd], tmp[j]);
            }
        }
        #pragma unroll
        for (int j = 0; j < 4; ++j) {
            const int bb = bg + 16 * j;
            const int addr = bb * (NO * NI) + o * NI + i0 + ii;
            bbuf[addr] = (ADD ? bbuf[addr] : 0.f) + tmp[j];
        }
    }
}

// -------- softmax over o (axis=1) of b -> c --------
__global__ __launch_bounds__(256) void softmax_kernel(const float* __restrict__ bbuf,
        float* __restrict__ cbuf) {
    const int bb = blockIdx.x >> 3;
    const int i = (blockIdx.x & 7) * 256 + threadIdx.x;
    const float* col = bbuf + bb * (NO * NI) + i;
    float m = -1e30f;
    for (int o = 0; o < NO; ++o) m = fmaxf(m, col[o * NI]);
    float s = 0.f;
    for (int o = 0; o < NO; ++o) s += __expf(col[o * NI] - m);
    const float inv = 1.f / s;
    float* outp = cbuf + bb * (NO * NI) + i;
    for (int o = 0; o < NO; ++o) outp[o * NI] = __expf(col[o * NI] - m) * inv;
}

extern "C" void kernel_launch(void* const* d_in, const int* in_sizes, int n_in,
                              void* d_out, int out_size, void* d_ws, size_t ws_size,
                              hipStream_t stream) {
    (void)in_sizes; (void)n_in; (void)out_size; (void)ws_size;
    const float* x      = (const float*)d_in[0];
    const float* conv_w = (const float*)d_in[1];
    const float* conv_b = (const float*)d_in[2];
    const float* pcap_w = (const float*)d_in[3];
    const float* pcap_b = (const float*)d_in[4];
    const float* W      = (const float*)d_in[5];
    float* out = (float*)d_out;
    float* ws  = (float*)d_ws;
    float* h   = ws + WS_H;
    float* u   = ws + WS_U;
    float* bbf = ws + WS_BB;
    float* cbf = ws + WS_CB;
    float* sp  = ws + WS_SP;
    float* v   = ws + WS_V;
    float* pp  = ws + WS_PP;   // overlaps bbf (dead until routing)
    float* wT  = ws + WS_WT;   // overlaps cbf (dead until routing)

    transpose_w_kernel<<<dim3(256, 4), 256, 0, stream>>>(pcap_w, wT);
    conv1_kernel<<<dim3(64, 16), 256, 0, stream>>>(x, conv_w, conv_b, h);
    conv2_partial_kernel<<<dim3(32, 4, 8), 256, 0, stream>>>(h, wT, pp);
    reduce_bias_squash_kernel<<<512, 256, 0, stream>>>(pp, pcap_b, u);
    // routing iter 0 (c uniform = 1/100)
    r_weighted_kernel<1><<<dim3(100, 16), 256, 0, stream>>>(W, u, nullptr, sp);
    squash_v_kernel<<<400, 256, 0, stream>>>(sp, v);
    r_logits_kernel<0><<<dim3(100, 16), 256, 0, stream>>>(W, u, v, bbf);
    // routing iter 1
    softmax_kernel<<<512, 256, 0, stream>>>(bbf, cbf);
    r_weighted_kernel<0><<<dim3(100, 16), 256, 0, stream>>>(W, u, cbf, sp);
    squash_v_kernel<<<400, 256, 0, stream>>>(sp, v);
    r_logits_kernel<1><<<dim3(100, 16), 256, 0, stream>>>(W, u, v, bbf);
    // routing iter 2
    softmax_kernel<<<512, 256, 0, stream>>>(bbf, cbf);
    r_weighted_kernel<0><<<dim3(100, 16), 256, 0, stream>>>(W, u, cbf, sp);
    squash_v_kernel<<<400, 256, 0, stream>>>(sp, out);
}